// Round 2
// baseline (607.567 us; speedup 1.0000x reference)
//
#include <hip/hip_runtime.h>
#include <hip/hip_bf16.h>
#include <math.h>

// ---------------------------------------------------------------------------
// CrossModalityMultiHeadAttention  (MI355X / gfx950)
// Round 2: fp32 in/out (reference dtype), bf16 MFMA internally (2% rel tol).
//   - inputs fp32 -> convert to bf16 while staging into LDS
//   - intermediates (hh, q/k/v, ctx) stored bf16 in workspace
//   - final output GEMMs write fp32 straight to d_out
//   - attention exploits sorted batch ids: contiguous key range per query,
//     online softmax, one wave per (head, query)
// ---------------------------------------------------------------------------

typedef __bf16 bf16x8 __attribute__((ext_vector_type(8)));
typedef float  f32x4  __attribute__((ext_vector_type(4)));

#define HID 512
#define NTOK 4096
#define BM 64
#define BN 64
#define BK 32
#define LDSS 40   // padded LDS stride: only 2-way bank aliasing (free)

// ------------------------------ range kernel -------------------------------
__global__ void compute_ranges(const int* __restrict__ bh,
                               const int* __restrict__ bt,
                               int n, int* __restrict__ out) {
    int t = threadIdx.x;
    if (t >= 128) return;
    int b = t & 63;
    const int* arr = (t < 64) ? bh : bt;
    int base = (t < 64) ? 0 : 128;
    int lo = 0, hi = n;
    while (lo < hi) { int mid = (lo + hi) >> 1; if (arr[mid] < b) lo = mid + 1; else hi = mid; }
    int start = lo;
    lo = 0; hi = n;
    while (lo < hi) { int mid = (lo + hi) >> 1; if (arr[mid] <= b) lo = mid + 1; else hi = mid; }
    out[base + b] = start;       // first index with value b
    out[base + 64 + b] = lo;     // one past last
}

// ------------------------------ GEMM + bias --------------------------------
// C[M,N] = A[M,K] @ W[K,N] + bias[N].  A: fp32 or bf16 (TA), W/bias fp32,
// C: fp32 or bf16 (TC). bf16 MFMA 16x16x32, fp32 accumulate.
template <typename TA, typename TC>
__global__ __launch_bounds__(256) void gemm_bias(
    const TA* __restrict__ A, int ldA,
    const float* __restrict__ W,
    const float* __restrict__ bias,
    TC* __restrict__ C,
    int M, int N, int K)
{
    __shared__ __align__(16) __bf16 As[BM][LDSS];
    __shared__ __align__(16) __bf16 Bs[BN][LDSS];   // stored [n][k]

    const int tid  = threadIdx.x;
    const int wave = tid >> 6;
    const int lane = tid & 63;
    const int quad = lane >> 4;
    const int l16  = lane & 15;
    const int rowBase = blockIdx.y * BM;
    const int colBase = blockIdx.x * BN;

    // staging assignments
    const int a_row = tid >> 2;            // 64 rows, 4 threads/row
    const int a_col = (tid & 3) * 8;       // 8 elements each
    const int b_k   = tid >> 3;            // 32 k, 8 threads/k
    const int b_n   = (tid & 7) * 8;       // 8 elements each

    f32x4 acc[4] = {};

    for (int kt = 0; kt < K; kt += BK) {
        // ---- stage A tile (64 x 32) as bf16 ----
        {
            const TA* Ap = A + (size_t)(rowBase + a_row) * ldA + kt + a_col;
            if constexpr (sizeof(TA) == 4) {      // fp32 A
                if (kt + a_col + 8 <= K) {
                    float4 f0 = *(const float4*)(Ap);
                    float4 f1 = *(const float4*)(Ap + 4);
                    bf16x8 v;
                    v[0]=(__bf16)f0.x; v[1]=(__bf16)f0.y; v[2]=(__bf16)f0.z; v[3]=(__bf16)f0.w;
                    v[4]=(__bf16)f1.x; v[5]=(__bf16)f1.y; v[6]=(__bf16)f1.z; v[7]=(__bf16)f1.w;
                    *(bf16x8*)&As[a_row][a_col] = v;
                } else {
                    #pragma unroll
                    for (int j = 0; j < 8; ++j) {
                        int k = kt + a_col + j;
                        As[a_row][a_col + j] = (k < K) ? (__bf16)Ap[j] : (__bf16)0.f;
                    }
                }
            } else {                               // bf16 A (always K%32==0 here)
                *(bf16x8*)&As[a_row][a_col] = *(const bf16x8*)Ap;
            }
        }
        // ---- stage B tile (32 x 64) fp32 -> bf16, transposed into Bs[n][k] ----
        {
            int k = kt + b_k;
            if (k < K) {
                const float* Wp = W + (size_t)k * N + colBase + b_n;
                float4 f0 = *(const float4*)(Wp);
                float4 f1 = *(const float4*)(Wp + 4);
                float fe[8] = {f0.x,f0.y,f0.z,f0.w,f1.x,f1.y,f1.z,f1.w};
                #pragma unroll
                for (int j = 0; j < 8; ++j) Bs[b_n + j][b_k] = (__bf16)fe[j];
            } else {
                #pragma unroll
                for (int j = 0; j < 8; ++j) Bs[b_n + j][b_k] = (__bf16)0.f;
            }
        }
        __syncthreads();

        // ---- MFMA: wave w does rows [w*16, w*16+16) x all 64 cols ----
        bf16x8 af = *(const bf16x8*)&As[wave * 16 + l16][quad * 8];
        #pragma unroll
        for (int c = 0; c < 4; ++c) {
            bf16x8 bf = *(const bf16x8*)&Bs[c * 16 + l16][quad * 8];
            acc[c] = __builtin_amdgcn_mfma_f32_16x16x32_bf16(af, bf, acc[c], 0, 0, 0);
        }
        __syncthreads();
    }

    // ---- epilogue: C/D layout col=lane&15, row=quad*4+reg ----
    #pragma unroll
    for (int c = 0; c < 4; ++c) {
        int col = colBase + c * 16 + l16;
        float bv = bias[col];
        #pragma unroll
        for (int r = 0; r < 4; ++r) {
            int row = rowBase + wave * 16 + quad * 4 + r;
            C[(size_t)row * N + col] = (TC)(acc[c][r] + bv);
        }
    }
}

// ------------------------------ attention ----------------------------------
// One wave per (query n, head h). Lane d owns dim d. Online softmax over the
// contiguous key range [ts, te) of this query's batch id. Out = Vres + P@Vctx.
__global__ __launch_bounds__(256) void attn(
    const __bf16* __restrict__ Q,     // [Nq, 512]
    const __bf16* __restrict__ Kk,    // [Nk, 512]
    const __bf16* __restrict__ Vres,  // [Nq, 512]
    const __bf16* __restrict__ Vctx,  // [Nk, 512]
    const int* __restrict__ qbatch,   // [Nq]
    const int* __restrict__ rstart,
    const int* __restrict__ rend,
    __bf16* __restrict__ Out,         // [Nq, 512]
    int Nq, int Nk)
{
    int wid  = blockIdx.x * 4 + (threadIdx.x >> 6);
    int lane = threadIdx.x & 63;
    int h = wid & 7;
    int n = wid >> 3;
    if (n >= Nq) return;

    size_t qoff = (size_t)n * HID + h * 64 + lane;
    float qd = (float)Q[qoff];
    int b  = qbatch[n];
    int ts = rstart[b], te = rend[b];

    float Mx = -__builtin_inff(), l = 0.f, acc = 0.f;
    if (ts < te) {
        for (int m = ts; m < te; ++m) {
            size_t koff = (size_t)m * HID + h * 64 + lane;
            float part = qd * (float)Kk[koff];
            #pragma unroll
            for (int off = 32; off > 0; off >>= 1)
                part += __shfl_xor(part, off, 64);
            float s  = part * 0.125f;               // / sqrt(64)
            float nM = fmaxf(Mx, s);
            float sc = __expf(Mx - nM);             // first iter: exp(-inf)=0
            float p  = __expf(s - nM);
            l   = l * sc + p;
            acc = acc * sc + p * (float)Vctx[koff];
            Mx  = nM;
        }
    } else {
        // all-masked row: softmax over all-NEG scores = uniform 1/Nk
        for (int m = 0; m < Nk; ++m)
            acc += (float)Vctx[(size_t)m * HID + h * 64 + lane];
        l = (float)Nk;
    }
    Out[qoff] = (__bf16)((float)Vres[qoff] + acc / l);
}

// ------------------------------ launcher -----------------------------------
extern "C" void kernel_launch(void* const* d_in, const int* in_sizes, int n_in,
                              void* d_out, int out_size, void* d_ws, size_t ws_size,
                              hipStream_t stream) {
    (void)in_sizes; (void)n_in; (void)out_size; (void)ws_size;

    const float* h_head = (const float*)d_in[0];   // [4096,300]
    const float* h_tail = (const float*)d_in[1];   // [4096,512]
    const int* batch_head = (const int*)d_in[2];
    const int* batch_tail = (const int*)d_in[3];
    const float* map_w = (const float*)d_in[4];
    const float* map_b = (const float*)d_in[5];
    const float* q1_w = (const float*)d_in[6];
    const float* q1_b = (const float*)d_in[7];
    const float* k1_w = (const float*)d_in[8];
    const float* k1_b = (const float*)d_in[9];
    const float* v1_w = (const float*)d_in[10];
    const float* v1_b = (const float*)d_in[11];
    const float* q2_w = (const float*)d_in[12];
    const float* q2_b = (const float*)d_in[13];
    const float* k2_w = (const float*)d_in[14];
    const float* k2_b = (const float*)d_in[15];
    const float* v2_w = (const float*)d_in[16];
    const float* v2_b = (const float*)d_in[17];
    const float* d1_w = (const float*)d_in[18];
    const float* d1_b = (const float*)d_in[19];
    const float* d2_w = (const float*)d_in[20];
    const float* d2_b = (const float*)d_in[21];

    float* out = (float*)d_out;

    const size_t SZ = (size_t)NTOK * HID;
    char* ws = (char*)d_ws;
    int* ranges = (int*)ws;                         // 256 ints
    __bf16* hh   = (__bf16*)(ws + 1024);
    __bf16* qh   = hh  + SZ;
    __bf16* kh   = qh  + SZ;
    __bf16* vh   = kh  + SZ;
    __bf16* qt   = vh  + SZ;
    __bf16* kt   = qt  + SZ;
    __bf16* vt   = kt  + SZ;
    __bf16* ctxh = vt  + SZ;
    __bf16* ctxt = ctxh + SZ;

    compute_ranges<<<dim3(1), dim3(128), 0, stream>>>(batch_head, batch_tail, NTOK, ranges);

    dim3 gblk(256);
    dim3 ggrd(HID / BN, NTOK / BM);   // (8, 64)

    // hh = h_head @ map_w + map_b   (fp32 A, bf16 out)
    gemm_bias<float, __bf16><<<ggrd, gblk, 0, stream>>>(h_head, 300, map_w, map_b, hh, NTOK, HID, 300);
    // head-side projections (from hh, bf16 A)
    gemm_bias<__bf16, __bf16><<<ggrd, gblk, 0, stream>>>(hh, HID, q1_w, q1_b, qh, NTOK, HID, HID);
    gemm_bias<__bf16, __bf16><<<ggrd, gblk, 0, stream>>>(hh, HID, k1_w, k1_b, kh, NTOK, HID, HID);
    gemm_bias<__bf16, __bf16><<<ggrd, gblk, 0, stream>>>(hh, HID, v1_w, v1_b, vh, NTOK, HID, HID);
    // tail-side projections (from h_tail, fp32 A)
    gemm_bias<float, __bf16><<<ggrd, gblk, 0, stream>>>(h_tail, HID, q2_w, q2_b, qt, NTOK, HID, HID);
    gemm_bias<float, __bf16><<<ggrd, gblk, 0, stream>>>(h_tail, HID, k2_w, k2_b, kt, NTOK, HID, HID);
    gemm_bias<float, __bf16><<<ggrd, gblk, 0, stream>>>(h_tail, HID, v2_w, v2_b, vt, NTOK, HID, HID);

    // attention: head queries attend to tail keys (ranges over batch_tail)
    dim3 ablk(256);
    dim3 agrd((NTOK * 8) / 4);        // one wave per (n, h)
    attn<<<agrd, ablk, 0, stream>>>(qh, kt, vh, vt, batch_head,
                                    ranges + 128, ranges + 192, ctxh, NTOK, NTOK);
    // tail queries attend to head keys (ranges over batch_head)
    attn<<<agrd, ablk, 0, stream>>>(qt, kh, vt, vh, batch_tail,
                                    ranges + 0, ranges + 64, ctxt, NTOK, NTOK);

    // output projections straight into d_out (out_head, then out_tail), fp32
    gemm_bias<__bf16, float><<<ggrd, gblk, 0, stream>>>(ctxh, HID, d1_w, d1_b, out, NTOK, HID, HID);
    gemm_bias<__bf16, float><<<ggrd, gblk, 0, stream>>>(ctxt, HID, d2_w, d2_b, out + SZ, NTOK, HID, HID);
}

// Round 3
// 336.672 us; speedup vs baseline: 1.8046x; 1.8046x over previous
//
#include <hip/hip_runtime.h>
#include <hip/hip_bf16.h>
#include <math.h>

// ---------------------------------------------------------------------------
// CrossModalityMultiHeadAttention  (MI355X / gfx950)
// Round 3: MFMA block-diagonal flash attention (batch ids sorted -> each
// query attends a contiguous key range; one block per (batch, head)).
// GEMM path unchanged from round 2 (passed, absmax 0.031).
// ---------------------------------------------------------------------------

typedef __bf16 bf16x8 __attribute__((ext_vector_type(8)));
typedef float  f32x4  __attribute__((ext_vector_type(4)));

#define HID 512
#define NTOK 4096
#define BM 64
#define BN 64
#define BK 32
#define LDSS 40   // GEMM LDS stride: only 2-way bank aliasing (free)

// ------------------------------ range kernel -------------------------------
__global__ void compute_ranges(const int* __restrict__ bh,
                               const int* __restrict__ bt,
                               int n, int* __restrict__ out) {
    int t = threadIdx.x;
    if (t >= 128) return;
    int b = t & 63;
    const int* arr = (t < 64) ? bh : bt;
    int base = (t < 64) ? 0 : 128;
    int lo = 0, hi = n;
    while (lo < hi) { int mid = (lo + hi) >> 1; if (arr[mid] < b) lo = mid + 1; else hi = mid; }
    int start = lo;
    lo = 0; hi = n;
    while (lo < hi) { int mid = (lo + hi) >> 1; if (arr[mid] <= b) lo = mid + 1; else hi = mid; }
    out[base + b] = start;       // first index with value b
    out[base + 64 + b] = lo;     // one past last
}

// ------------------------------ GEMM + bias --------------------------------
template <typename TA, typename TC>
__global__ __launch_bounds__(256) void gemm_bias(
    const TA* __restrict__ A, int ldA,
    const float* __restrict__ W,
    const float* __restrict__ bias,
    TC* __restrict__ C,
    int M, int N, int K)
{
    __shared__ __align__(16) __bf16 As[BM][LDSS];
    __shared__ __align__(16) __bf16 Bs[BN][LDSS];   // stored [n][k]

    const int tid  = threadIdx.x;
    const int wave = tid >> 6;
    const int lane = tid & 63;
    const int quad = lane >> 4;
    const int l16  = lane & 15;
    const int rowBase = blockIdx.y * BM;
    const int colBase = blockIdx.x * BN;

    const int a_row = tid >> 2;
    const int a_col = (tid & 3) * 8;
    const int b_k   = tid >> 3;
    const int b_n   = (tid & 7) * 8;

    f32x4 acc[4] = {};

    for (int kt = 0; kt < K; kt += BK) {
        {
            const TA* Ap = A + (size_t)(rowBase + a_row) * ldA + kt + a_col;
            if constexpr (sizeof(TA) == 4) {
                if (kt + a_col + 8 <= K) {
                    float4 f0 = *(const float4*)(Ap);
                    float4 f1 = *(const float4*)(Ap + 4);
                    bf16x8 v;
                    v[0]=(__bf16)f0.x; v[1]=(__bf16)f0.y; v[2]=(__bf16)f0.z; v[3]=(__bf16)f0.w;
                    v[4]=(__bf16)f1.x; v[5]=(__bf16)f1.y; v[6]=(__bf16)f1.z; v[7]=(__bf16)f1.w;
                    *(bf16x8*)&As[a_row][a_col] = v;
                } else {
                    #pragma unroll
                    for (int j = 0; j < 8; ++j) {
                        int k = kt + a_col + j;
                        As[a_row][a_col + j] = (k < K) ? (__bf16)Ap[j] : (__bf16)0.f;
                    }
                }
            } else {
                *(bf16x8*)&As[a_row][a_col] = *(const bf16x8*)Ap;
            }
        }
        {
            int k = kt + b_k;
            if (k < K) {
                const float* Wp = W + (size_t)k * N + colBase + b_n;
                float4 f0 = *(const float4*)(Wp);
                float4 f1 = *(const float4*)(Wp + 4);
                float fe[8] = {f0.x,f0.y,f0.z,f0.w,f1.x,f1.y,f1.z,f1.w};
                #pragma unroll
                for (int j = 0; j < 8; ++j) Bs[b_n + j][b_k] = (__bf16)fe[j];
            } else {
                #pragma unroll
                for (int j = 0; j < 8; ++j) Bs[b_n + j][b_k] = (__bf16)0.f;
            }
        }
        __syncthreads();

        bf16x8 af = *(const bf16x8*)&As[wave * 16 + l16][quad * 8];
        #pragma unroll
        for (int c = 0; c < 4; ++c) {
            bf16x8 bf = *(const bf16x8*)&Bs[c * 16 + l16][quad * 8];
            acc[c] = __builtin_amdgcn_mfma_f32_16x16x32_bf16(af, bf, acc[c], 0, 0, 0);
        }
        __syncthreads();
    }

    #pragma unroll
    for (int c = 0; c < 4; ++c) {
        int col = colBase + c * 16 + l16;
        float bv = bias[col];
        #pragma unroll
        for (int r = 0; r < 4; ++r) {
            int row = rowBase + wave * 16 + quad * 4 + r;
            C[(size_t)row * N + col] = (TC)(acc[c][r] + bv);
        }
    }
}

// ------------------------- MFMA flash attention ----------------------------
// One block per (batch b, head h). Queries [qs,qe), keys [ts,te) — both
// contiguous because batch ids are sorted. Per 64-query chunk: 4 waves x 16
// rows; loop key chunks of 64 with online softmax.
// Layouts (16x16x32 bf16 MFMA):
//   A-frag: A[m=l16][k=quad*8+j] ; B-frag: B[n=l16][k=quad*8+j]
//   C/D   : col=l16, row=quad*4+reg
__global__ __launch_bounds__(256) void attn_mfma(
    const __bf16* __restrict__ Q,     // [Nq, 512]
    const __bf16* __restrict__ Kg,    // [Nk, 512]
    const __bf16* __restrict__ Vres,  // [Nq, 512]
    const __bf16* __restrict__ Vctx,  // [Nk, 512]
    const int* __restrict__ qstart, const int* __restrict__ qend,
    const int* __restrict__ kstart, const int* __restrict__ kend,
    __bf16* __restrict__ Out,         // [Nq, 512]
    int Nq, int Nk)
{
    __shared__ __align__(16) __bf16 Qs[64][72];
    __shared__ __align__(16) __bf16 Ks[64][72];
    __shared__ __align__(16) __bf16 Vt[64][72];   // [dim][key]
    __shared__ __align__(16) __bf16 Ps[64][72];   // [query][key]

    const int h = blockIdx.x, b = blockIdx.y;
    const int qs = qstart[b], qe = qend[b];
    const int ts = kstart[b], te = kend[b];
    const int nq = qe - qs, nk = te - ts;
    if (nq <= 0) return;

    const int tid  = threadIdx.x;
    const int wave = tid >> 6;
    const int lane = tid & 63;
    const int quad = lane >> 4;
    const int l16  = lane & 15;
    const int srow = tid >> 2;            // staging: 64 rows, 4 threads/row
    const int scol = (tid & 3) * 16;      // 16 bf16 (32 B) each

    if (nk <= 0) {
        // softmax over all-NEG scores = uniform 1/Nk over ALL keys
        float* meanv = (float*)Qs;
        if (tid < 64) {
            float s = 0.f;
            for (int m = 0; m < Nk; ++m)
                s += (float)Vctx[(size_t)m * HID + h * 64 + tid];
            meanv[tid] = s / (float)Nk;
        }
        __syncthreads();
        int d = tid & 63;
        for (int r = qs + (tid >> 6); r < qe; r += 4) {
            size_t off = (size_t)r * HID + h * 64 + d;
            Out[off] = (__bf16)((float)Vres[off] + meanv[d]);
        }
        return;
    }

    for (int qc = 0; qc < nq; qc += 64) {
        __syncthreads();   // previous chunk's Qs reads done
        {
            int qg = min(qs + qc + srow, Nq - 1);
            const __bf16* src = Q + (size_t)qg * HID + h * 64 + scol;
            *(bf16x8*)&Qs[srow][scol]     = *(const bf16x8*)src;
            *(bf16x8*)&Qs[srow][scol + 8] = *(const bf16x8*)(src + 8);
        }
        __syncthreads();
        bf16x8 aq0 = *(const bf16x8*)&Qs[wave * 16 + l16][quad * 8];
        bf16x8 aq1 = *(const bf16x8*)&Qs[wave * 16 + l16][32 + quad * 8];

        f32x4 O[4] = {};
        float Mx[4], L[4];
        #pragma unroll
        for (int r = 0; r < 4; ++r) { Mx[r] = -__builtin_inff(); L[r] = 0.f; }

        for (int kc = 0; kc < nk; kc += 64) {
            __syncthreads();   // previous chunk's Ks/Vt reads done
            {
                int kg = min(ts + kc + srow, Nk - 1);
                const __bf16* ksrc = Kg + (size_t)kg * HID + h * 64 + scol;
                *(bf16x8*)&Ks[srow][scol]     = *(const bf16x8*)ksrc;
                *(bf16x8*)&Ks[srow][scol + 8] = *(const bf16x8*)(ksrc + 8);
                const __bf16* vsrc = Vctx + (size_t)kg * HID + h * 64 + scol;
                bf16x8 v0 = *(const bf16x8*)vsrc;
                bf16x8 v1 = *(const bf16x8*)(vsrc + 8);
                #pragma unroll
                for (int j = 0; j < 8; ++j) {
                    Vt[scol + j][srow]     = v0[j];
                    Vt[scol + 8 + j][srow] = v1[j];
                }
            }
            __syncthreads();

            // S = Q @ K^T  (this wave: 16 q x 64 k)
            f32x4 S[4] = {};
            #pragma unroll
            for (int c = 0; c < 4; ++c) {
                bf16x8 bk0 = *(const bf16x8*)&Ks[c * 16 + l16][quad * 8];
                bf16x8 bk1 = *(const bf16x8*)&Ks[c * 16 + l16][32 + quad * 8];
                S[c] = __builtin_amdgcn_mfma_f32_16x16x32_bf16(aq0, bk0, S[c], 0, 0, 0);
                S[c] = __builtin_amdgcn_mfma_f32_16x16x32_bf16(aq1, bk1, S[c], 0, 0, 0);
            }

            // scale + mask trailing keys
            #pragma unroll
            for (int c = 0; c < 4; ++c) {
                bool valid = (ts + kc + c * 16 + l16) < te;
                #pragma unroll
                for (int r = 0; r < 4; ++r)
                    S[c][r] = valid ? S[c][r] * 0.125f : -__builtin_inff();
            }

            // chunk row-max (across c, then across the 16 lanes of the quad)
            float cm[4], ps[4], alpha[4];
            #pragma unroll
            for (int r = 0; r < 4; ++r) {
                float v = fmaxf(fmaxf(S[0][r], S[1][r]), fmaxf(S[2][r], S[3][r]));
                v = fmaxf(v, __shfl_xor(v, 1, 64));
                v = fmaxf(v, __shfl_xor(v, 2, 64));
                v = fmaxf(v, __shfl_xor(v, 4, 64));
                v = fmaxf(v, __shfl_xor(v, 8, 64));
                cm[r] = v;
            }
            #pragma unroll
            for (int r = 0; r < 4; ++r) {
                float nM = fmaxf(Mx[r], cm[r]);         // finite: >=1 valid key
                alpha[r] = __expf(Mx[r] - nM);          // first chunk: exp(-inf)=0
                Mx[r] = nM;
                ps[r] = 0.f;
            }
            #pragma unroll
            for (int c = 0; c < 4; ++c)
                #pragma unroll
                for (int r = 0; r < 4; ++r) {
                    float p = __expf(S[c][r] - Mx[r]);  // masked: exp(-inf)=0
                    S[c][r] = p;
                    ps[r] += p;
                }
            #pragma unroll
            for (int r = 0; r < 4; ++r) {
                float v = ps[r];
                v += __shfl_xor(v, 1, 64);
                v += __shfl_xor(v, 2, 64);
                v += __shfl_xor(v, 4, 64);
                v += __shfl_xor(v, 8, 64);
                L[r] = L[r] * alpha[r] + v;
            }
            #pragma unroll
            for (int c = 0; c < 4; ++c)
                #pragma unroll
                for (int r = 0; r < 4; ++r)
                    O[c][r] *= alpha[r];

            // P -> LDS (C layout -> memory) for A-frag reload
            #pragma unroll
            for (int c = 0; c < 4; ++c)
                #pragma unroll
                for (int r = 0; r < 4; ++r)
                    Ps[wave * 16 + quad * 4 + r][c * 16 + l16] = (__bf16)S[c][r];
            __syncthreads();

            // O += P @ V
            bf16x8 ap0 = *(const bf16x8*)&Ps[wave * 16 + l16][quad * 8];
            bf16x8 ap1 = *(const bf16x8*)&Ps[wave * 16 + l16][32 + quad * 8];
            #pragma unroll
            for (int c = 0; c < 4; ++c) {
                bf16x8 bv0 = *(const bf16x8*)&Vt[c * 16 + l16][quad * 8];
                bf16x8 bv1 = *(const bf16x8*)&Vt[c * 16 + l16][32 + quad * 8];
                O[c] = __builtin_amdgcn_mfma_f32_16x16x32_bf16(ap0, bv0, O[c], 0, 0, 0);
                O[c] = __builtin_amdgcn_mfma_f32_16x16x32_bf16(ap1, bv1, O[c], 0, 0, 0);
            }
        }

        // epilogue: Out = Vres + O / L
        #pragma unroll
        for (int c = 0; c < 4; ++c) {
            int d = h * 64 + c * 16 + l16;
            #pragma unroll
            for (int r = 0; r < 4; ++r) {
                int qrow = qs + qc + wave * 16 + quad * 4 + r;
                if (qrow < qe) {
                    size_t off = (size_t)qrow * HID + d;
                    Out[off] = (__bf16)((float)Vres[off] + O[c][r] / L[r]);
                }
            }
        }
    }
}

// ------------------------------ launcher -----------------------------------
extern "C" void kernel_launch(void* const* d_in, const int* in_sizes, int n_in,
                              void* d_out, int out_size, void* d_ws, size_t ws_size,
                              hipStream_t stream) {
    (void)in_sizes; (void)n_in; (void)out_size; (void)ws_size;

    const float* h_head = (const float*)d_in[0];   // [4096,300]
    const float* h_tail = (const float*)d_in[1];   // [4096,512]
    const int* batch_head = (const int*)d_in[2];
    const int* batch_tail = (const int*)d_in[3];
    const float* map_w = (const float*)d_in[4];
    const float* map_b = (const float*)d_in[5];
    const float* q1_w = (const float*)d_in[6];
    const float* q1_b = (const float*)d_in[7];
    const float* k1_w = (const float*)d_in[8];
    const float* k1_b = (const float*)d_in[9];
    const float* v1_w = (const float*)d_in[10];
    const float* v1_b = (const float*)d_in[11];
    const float* q2_w = (const float*)d_in[12];
    const float* q2_b = (const float*)d_in[13];
    const float* k2_w = (const float*)d_in[14];
    const float* k2_b = (const float*)d_in[15];
    const float* v2_w = (const float*)d_in[16];
    const float* v2_b = (const float*)d_in[17];
    const float* d1_w = (const float*)d_in[18];
    const float* d1_b = (const float*)d_in[19];
    const float* d2_w = (const float*)d_in[20];
    const float* d2_b = (const float*)d_in[21];

    float* out = (float*)d_out;

    const size_t SZ = (size_t)NTOK * HID;
    char* ws = (char*)d_ws;
    int* ranges = (int*)ws;                         // 256 ints
    __bf16* hh   = (__bf16*)(ws + 1024);
    __bf16* qh   = hh  + SZ;
    __bf16* kh   = qh  + SZ;
    __bf16* vh   = kh  + SZ;
    __bf16* qt   = vh  + SZ;
    __bf16* kt   = qt  + SZ;
    __bf16* vt   = kt  + SZ;
    __bf16* ctxh = vt  + SZ;
    __bf16* ctxt = ctxh + SZ;

    compute_ranges<<<dim3(1), dim3(128), 0, stream>>>(batch_head, batch_tail, NTOK, ranges);

    dim3 gblk(256);
    dim3 ggrd(HID / BN, NTOK / BM);   // (8, 64)

    gemm_bias<float, __bf16><<<ggrd, gblk, 0, stream>>>(h_head, 300, map_w, map_b, hh, NTOK, HID, 300);
    gemm_bias<__bf16, __bf16><<<ggrd, gblk, 0, stream>>>(hh, HID, q1_w, q1_b, qh, NTOK, HID, HID);
    gemm_bias<__bf16, __bf16><<<ggrd, gblk, 0, stream>>>(hh, HID, k1_w, k1_b, kh, NTOK, HID, HID);
    gemm_bias<__bf16, __bf16><<<ggrd, gblk, 0, stream>>>(hh, HID, v1_w, v1_b, vh, NTOK, HID, HID);
    gemm_bias<float, __bf16><<<ggrd, gblk, 0, stream>>>(h_tail, HID, q2_w, q2_b, qt, NTOK, HID, HID);
    gemm_bias<float, __bf16><<<ggrd, gblk, 0, stream>>>(h_tail, HID, k2_w, k2_b, kt, NTOK, HID, HID);
    gemm_bias<float, __bf16><<<ggrd, gblk, 0, stream>>>(h_tail, HID, v2_w, v2_b, vt, NTOK, HID, HID);

    // attention (block-diagonal flash): grid = (head, batch)
    dim3 ablk(256);
    dim3 agrd(8, 64);
    // head queries [ranges+0/+64) attend tail keys [ranges+128/+192)
    attn_mfma<<<agrd, ablk, 0, stream>>>(qh, kt, vh, vt,
                                         ranges + 0, ranges + 64,
                                         ranges + 128, ranges + 192,
                                         ctxh, NTOK, NTOK);
    // tail queries attend head keys
    attn_mfma<<<agrd, ablk, 0, stream>>>(qt, kh, vt, vh,
                                         ranges + 128, ranges + 192,
                                         ranges + 0, ranges + 64,
                                         ctxt, NTOK, NTOK);

    gemm_bias<__bf16, float><<<ggrd, gblk, 0, stream>>>(ctxh, HID, d1_w, d1_b, out, NTOK, HID, HID);
    gemm_bias<__bf16, float><<<ggrd, gblk, 0, stream>>>(ctxt, HID, d2_w, d2_b, out + SZ, NTOK, HID, HID);
}

// Round 4
// 207.417 us; speedup vs baseline: 2.9292x; 1.6232x over previous
//
#include <hip/hip_runtime.h>
#include <hip/hip_bf16.h>
#include <math.h>

// ---------------------------------------------------------------------------
// CrossModalityMultiHeadAttention  (MI355X / gfx950)
// Round 4:
//   - weights pre-transposed to bf16 WT[N][Kpad] in one fused dispatch
//     -> GEMM B-staging is a single bf16x8 load + ds_write_b128 (no scalar
//        transpose in the K-loop)
//   - dispatch fusion via grid.z: map / qkv-head / qkv-tail / out-proj
//     (9 GEMM launches -> 4), both attentions in one launch
//   - attention: MFMA block-diagonal flash (round 3, unchanged math)
// ---------------------------------------------------------------------------

typedef __bf16 bf16x8 __attribute__((ext_vector_type(8)));
typedef float  f32x4  __attribute__((ext_vector_type(4)));

#define HID 512
#define NTOK 4096
#define BM 64
#define BN 64
#define BK 32
#define LDSS 40   // GEMM LDS stride: only 2-way bank aliasing (free)

// ------------------------------ range kernel -------------------------------
__global__ void compute_ranges(const int* __restrict__ bh,
                               const int* __restrict__ bt,
                               int n, int* __restrict__ out) {
    int t = threadIdx.x;
    if (t >= 128) return;
    int b = t & 63;
    const int* arr = (t < 64) ? bh : bt;
    int base = (t < 64) ? 0 : 128;
    int lo = 0, hi = n;
    while (lo < hi) { int mid = (lo + hi) >> 1; if (arr[mid] < b) lo = mid + 1; else hi = mid; }
    int start = lo;
    lo = 0; hi = n;
    while (lo < hi) { int mid = (lo + hi) >> 1; if (arr[mid] <= b) lo = mid + 1; else hi = mid; }
    out[base + b] = start;
    out[base + 64 + b] = lo;
}

// --------------------------- weight transpose ------------------------------
// W[K][512] fp32 -> WT[512][ldT] bf16 (rows zero-padded K..ldT).
struct TransJobs {
    const float* src[9];
    __bf16*      dst[9];
    int          K[9];
    int          ldT[9];
};

__global__ __launch_bounds__(256) void transpose_weights(TransJobs tj) {
    const int z = blockIdx.z;
    const float* src = tj.src[z];
    __bf16* dst = tj.dst[z];
    const int K = tj.K[z], ldT = tj.ldT[z];
    const int tk = blockIdx.y * 64;
    const int tn = blockIdx.x * 64;
    if (tk >= ldT) return;

    __shared__ __bf16 T[64][72];
    const int tid = threadIdx.x;
    const int r0 = tid >> 4;           // 0..15
    const int c0 = (tid & 15) * 4;     // 0..60
    #pragma unroll
    for (int i = 0; i < 4; ++i) {
        int k = tk + r0 + i * 16;
        float4 v = (k < K) ? *(const float4*)&src[(size_t)k * 512 + tn + c0]
                           : float4{0.f, 0.f, 0.f, 0.f};
        T[r0 + i * 16][c0 + 0] = (__bf16)v.x;
        T[r0 + i * 16][c0 + 1] = (__bf16)v.y;
        T[r0 + i * 16][c0 + 2] = (__bf16)v.z;
        T[r0 + i * 16][c0 + 3] = (__bf16)v.w;
    }
    __syncthreads();

    const int n  = tid >> 2;           // output row (col of W)
    const int kk = (tid & 3) * 16;     // 16 k each
    bf16x8 o0, o1;
    #pragma unroll
    for (int j = 0; j < 8; ++j) { o0[j] = T[kk + j][n]; o1[j] = T[kk + 8 + j][n]; }
    __bf16* dp = dst + (size_t)(tn + n) * ldT + tk + kk;
    *(bf16x8*)dp       = o0;
    *(bf16x8*)(dp + 8) = o1;
}

// ------------------------------ GEMM + bias --------------------------------
// C[z][4096,512] = A[z] @ WT[z]^T + bias[z]; z = blockIdx.z selects job.
// WT is bf16 [512][Kpad] (pre-transposed, zero-padded). A fp32 or bf16.
template <typename TA, typename TC>
__global__ __launch_bounds__(256) void gemm3(
    const TA* __restrict__ A0, const TA* __restrict__ A1, const TA* __restrict__ A2,
    int ldA,
    const __bf16* __restrict__ W0, const __bf16* __restrict__ W1, const __bf16* __restrict__ W2,
    const float* __restrict__ B0, const float* __restrict__ B1, const float* __restrict__ B2,
    TC* __restrict__ C0, TC* __restrict__ C1, TC* __restrict__ C2,
    int Kreal, int Kpad)
{
    __shared__ __align__(16) __bf16 As[BM][LDSS];
    __shared__ __align__(16) __bf16 Bs[BN][LDSS];   // [n][k]

    const int z = blockIdx.z;
    const TA*     A    = z == 0 ? A0 : (z == 1 ? A1 : A2);
    const __bf16* WT   = z == 0 ? W0 : (z == 1 ? W1 : W2);
    const float*  bias = z == 0 ? B0 : (z == 1 ? B1 : B2);
    TC*           C    = z == 0 ? C0 : (z == 1 ? C1 : C2);

    const int tid  = threadIdx.x;
    const int wave = tid >> 6;
    const int lane = tid & 63;
    const int quad = lane >> 4;
    const int l16  = lane & 15;
    const int rowBase = blockIdx.y * BM;
    const int colBase = blockIdx.x * BN;

    const int s_row = tid >> 2;           // 64 rows, 4 threads/row
    const int s_col = (tid & 3) * 8;      // 8 elements (16 B) each

    f32x4 acc[4] = {};

    for (int kt = 0; kt < Kpad; kt += BK) {
        // ---- stage A tile (64 x 32) as bf16 ----
        {
            const TA* Ap = A + (size_t)(rowBase + s_row) * ldA + kt + s_col;
            if constexpr (sizeof(TA) == 4) {          // fp32 A
                if (kt + s_col + 8 <= Kreal) {
                    float4 f0 = *(const float4*)(Ap);
                    float4 f1 = *(const float4*)(Ap + 4);
                    bf16x8 v;
                    v[0]=(__bf16)f0.x; v[1]=(__bf16)f0.y; v[2]=(__bf16)f0.z; v[3]=(__bf16)f0.w;
                    v[4]=(__bf16)f1.x; v[5]=(__bf16)f1.y; v[6]=(__bf16)f1.z; v[7]=(__bf16)f1.w;
                    *(bf16x8*)&As[s_row][s_col] = v;
                } else {
                    #pragma unroll
                    for (int j = 0; j < 8; ++j) {
                        int k = kt + s_col + j;
                        As[s_row][s_col + j] = (k < Kreal) ? (__bf16)Ap[j] : (__bf16)0.f;
                    }
                }
            } else {                                   // bf16 A (Kreal==Kpad)
                *(bf16x8*)&As[s_row][s_col] = *(const bf16x8*)Ap;
            }
        }
        // ---- stage B tile: WT rows are ready-to-use bf16 [n][k] ----
        {
            const __bf16* Wp = WT + (size_t)(colBase + s_row) * Kpad + kt + s_col;
            *(bf16x8*)&Bs[s_row][s_col] = *(const bf16x8*)Wp;
        }
        __syncthreads();

        bf16x8 af = *(const bf16x8*)&As[wave * 16 + l16][quad * 8];
        #pragma unroll
        for (int c = 0; c < 4; ++c) {
            bf16x8 bf = *(const bf16x8*)&Bs[c * 16 + l16][quad * 8];
            acc[c] = __builtin_amdgcn_mfma_f32_16x16x32_bf16(af, bf, acc[c], 0, 0, 0);
        }
        __syncthreads();
    }

    #pragma unroll
    for (int c = 0; c < 4; ++c) {
        int col = colBase + c * 16 + l16;
        float bv = bias[col];
        #pragma unroll
        for (int r = 0; r < 4; ++r) {
            int row = rowBase + wave * 16 + quad * 4 + r;
            C[(size_t)row * HID + col] = (TC)(acc[c][r] + bv);
        }
    }
}

// ------------------------- MFMA flash attention ----------------------------
// grid = (head 8, batch 64, side 2). side 0: head-q x tail-k; side 1: swap.
__global__ __launch_bounds__(256) void attn_mfma(
    const __bf16* __restrict__ Q0, const __bf16* __restrict__ K0,
    const __bf16* __restrict__ Vr0, const __bf16* __restrict__ Vc0,
    const __bf16* __restrict__ Q1, const __bf16* __restrict__ K1,
    const __bf16* __restrict__ Vr1, const __bf16* __restrict__ Vc1,
    const int* __restrict__ ranges,
    __bf16* __restrict__ O0, __bf16* __restrict__ O1,
    int Nq, int Nk)
{
    __shared__ __align__(16) __bf16 Qs[64][72];
    __shared__ __align__(16) __bf16 Ks[64][72];
    __shared__ __align__(16) __bf16 Vt[64][72];   // [dim][key]
    __shared__ __align__(16) __bf16 Ps[64][72];   // [query][key]

    const int z = blockIdx.z;
    const __bf16* Q    = z ? Q1 : Q0;
    const __bf16* Kg   = z ? K1 : K0;
    const __bf16* Vres = z ? Vr1 : Vr0;
    const __bf16* Vctx = z ? Vc1 : Vc0;
    __bf16* Out        = z ? O1 : O0;
    const int* qstart  = z ? ranges + 128 : ranges;
    const int* qend    = z ? ranges + 192 : ranges + 64;
    const int* kstart  = z ? ranges       : ranges + 128;
    const int* kend    = z ? ranges + 64  : ranges + 192;

    const int h = blockIdx.x, b = blockIdx.y;
    const int qs = qstart[b], qe = qend[b];
    const int ts = kstart[b], te = kend[b];
    const int nq = qe - qs, nk = te - ts;
    if (nq <= 0) return;

    const int tid  = threadIdx.x;
    const int wave = tid >> 6;
    const int lane = tid & 63;
    const int quad = lane >> 4;
    const int l16  = lane & 15;
    const int srow = tid >> 2;
    const int scol = (tid & 3) * 16;

    if (nk <= 0) {
        // softmax over all-NEG scores = uniform 1/Nk over ALL keys
        float* meanv = (float*)Qs;
        if (tid < 64) {
            float s = 0.f;
            for (int m = 0; m < Nk; ++m)
                s += (float)Vctx[(size_t)m * HID + h * 64 + tid];
            meanv[tid] = s / (float)Nk;
        }
        __syncthreads();
        int d = tid & 63;
        for (int r = qs + (tid >> 6); r < qe; r += 4) {
            size_t off = (size_t)r * HID + h * 64 + d;
            Out[off] = (__bf16)((float)Vres[off] + meanv[d]);
        }
        return;
    }

    for (int qc = 0; qc < nq; qc += 64) {
        __syncthreads();
        {
            int qg = min(qs + qc + srow, Nq - 1);
            const __bf16* src = Q + (size_t)qg * HID + h * 64 + scol;
            *(bf16x8*)&Qs[srow][scol]     = *(const bf16x8*)src;
            *(bf16x8*)&Qs[srow][scol + 8] = *(const bf16x8*)(src + 8);
        }
        __syncthreads();
        bf16x8 aq0 = *(const bf16x8*)&Qs[wave * 16 + l16][quad * 8];
        bf16x8 aq1 = *(const bf16x8*)&Qs[wave * 16 + l16][32 + quad * 8];

        f32x4 O[4] = {};
        float Mx[4], L[4];
        #pragma unroll
        for (int r = 0; r < 4; ++r) { Mx[r] = -__builtin_inff(); L[r] = 0.f; }

        for (int kc = 0; kc < nk; kc += 64) {
            __syncthreads();
            {
                int kg = min(ts + kc + srow, Nk - 1);
                const __bf16* ksrc = Kg + (size_t)kg * HID + h * 64 + scol;
                *(bf16x8*)&Ks[srow][scol]     = *(const bf16x8*)ksrc;
                *(bf16x8*)&Ks[srow][scol + 8] = *(const bf16x8*)(ksrc + 8);
                const __bf16* vsrc = Vctx + (size_t)kg * HID + h * 64 + scol;
                bf16x8 v0 = *(const bf16x8*)vsrc;
                bf16x8 v1 = *(const bf16x8*)(vsrc + 8);
                #pragma unroll
                for (int j = 0; j < 8; ++j) {
                    Vt[scol + j][srow]     = v0[j];
                    Vt[scol + 8 + j][srow] = v1[j];
                }
            }
            __syncthreads();

            f32x4 S[4] = {};
            #pragma unroll
            for (int c = 0; c < 4; ++c) {
                bf16x8 bk0 = *(const bf16x8*)&Ks[c * 16 + l16][quad * 8];
                bf16x8 bk1 = *(const bf16x8*)&Ks[c * 16 + l16][32 + quad * 8];
                S[c] = __builtin_amdgcn_mfma_f32_16x16x32_bf16(aq0, bk0, S[c], 0, 0, 0);
                S[c] = __builtin_amdgcn_mfma_f32_16x16x32_bf16(aq1, bk1, S[c], 0, 0, 0);
            }

            #pragma unroll
            for (int c = 0; c < 4; ++c) {
                bool valid = (ts + kc + c * 16 + l16) < te;
                #pragma unroll
                for (int r = 0; r < 4; ++r)
                    S[c][r] = valid ? S[c][r] * 0.125f : -__builtin_inff();
            }

            float cm[4], ps[4], alpha[4];
            #pragma unroll
            for (int r = 0; r < 4; ++r) {
                float v = fmaxf(fmaxf(S[0][r], S[1][r]), fmaxf(S[2][r], S[3][r]));
                v = fmaxf(v, __shfl_xor(v, 1, 64));
                v = fmaxf(v, __shfl_xor(v, 2, 64));
                v = fmaxf(v, __shfl_xor(v, 4, 64));
                v = fmaxf(v, __shfl_xor(v, 8, 64));
                cm[r] = v;
            }
            #pragma unroll
            for (int r = 0; r < 4; ++r) {
                float nM = fmaxf(Mx[r], cm[r]);
                alpha[r] = __expf(Mx[r] - nM);
                Mx[r] = nM;
                ps[r] = 0.f;
            }
            #pragma unroll
            for (int c = 0; c < 4; ++c)
                #pragma unroll
                for (int r = 0; r < 4; ++r) {
                    float p = __expf(S[c][r] - Mx[r]);
                    S[c][r] = p;
                    ps[r] += p;
                }
            #pragma unroll
            for (int r = 0; r < 4; ++r) {
                float v = ps[r];
                v += __shfl_xor(v, 1, 64);
                v += __shfl_xor(v, 2, 64);
                v += __shfl_xor(v, 4, 64);
                v += __shfl_xor(v, 8, 64);
                L[r] = L[r] * alpha[r] + v;
            }
            #pragma unroll
            for (int c = 0; c < 4; ++c)
                #pragma unroll
                for (int r = 0; r < 4; ++r)
                    O[c][r] *= alpha[r];

            #pragma unroll
            for (int c = 0; c < 4; ++c)
                #pragma unroll
                for (int r = 0; r < 4; ++r)
                    Ps[wave * 16 + quad * 4 + r][c * 16 + l16] = (__bf16)S[c][r];
            __syncthreads();

            bf16x8 ap0 = *(const bf16x8*)&Ps[wave * 16 + l16][quad * 8];
            bf16x8 ap1 = *(const bf16x8*)&Ps[wave * 16 + l16][32 + quad * 8];
            #pragma unroll
            for (int c = 0; c < 4; ++c) {
                bf16x8 bv0 = *(const bf16x8*)&Vt[c * 16 + l16][quad * 8];
                bf16x8 bv1 = *(const bf16x8*)&Vt[c * 16 + l16][32 + quad * 8];
                O[c] = __builtin_amdgcn_mfma_f32_16x16x32_bf16(ap0, bv0, O[c], 0, 0, 0);
                O[c] = __builtin_amdgcn_mfma_f32_16x16x32_bf16(ap1, bv1, O[c], 0, 0, 0);
            }
        }

        #pragma unroll
        for (int c = 0; c < 4; ++c) {
            int d = h * 64 + c * 16 + l16;
            #pragma unroll
            for (int r = 0; r < 4; ++r) {
                int qrow = qs + qc + wave * 16 + quad * 4 + r;
                if (qrow < qe) {
                    size_t off = (size_t)qrow * HID + d;
                    Out[off] = (__bf16)((float)Vres[off] + O[c][r] / L[r]);
                }
            }
        }
    }
}

// ------------------------------ launcher -----------------------------------
extern "C" void kernel_launch(void* const* d_in, const int* in_sizes, int n_in,
                              void* d_out, int out_size, void* d_ws, size_t ws_size,
                              hipStream_t stream) {
    (void)in_sizes; (void)n_in; (void)out_size; (void)ws_size;

    const float* h_head = (const float*)d_in[0];   // [4096,300]
    const float* h_tail = (const float*)d_in[1];   // [4096,512]
    const int* batch_head = (const int*)d_in[2];
    const int* batch_tail = (const int*)d_in[3];
    const float* map_w = (const float*)d_in[4];
    const float* map_b = (const float*)d_in[5];
    const float* q1_w = (const float*)d_in[6];
    const float* q1_b = (const float*)d_in[7];
    const float* k1_w = (const float*)d_in[8];
    const float* k1_b = (const float*)d_in[9];
    const float* v1_w = (const float*)d_in[10];
    const float* v1_b = (const float*)d_in[11];
    const float* q2_w = (const float*)d_in[12];
    const float* q2_b = (const float*)d_in[13];
    const float* k2_w = (const float*)d_in[14];
    const float* k2_b = (const float*)d_in[15];
    const float* v2_w = (const float*)d_in[16];
    const float* v2_b = (const float*)d_in[17];
    const float* d1_w = (const float*)d_in[18];
    const float* d1_b = (const float*)d_in[19];
    const float* d2_w = (const float*)d_in[20];
    const float* d2_b = (const float*)d_in[21];

    float* out = (float*)d_out;

    const size_t SZ = (size_t)NTOK * HID;
    char* ws = (char*)d_ws;
    int* ranges = (int*)ws;                         // 256 ints
    __bf16* hh   = (__bf16*)(ws + 1024);
    __bf16* qh   = hh  + SZ;
    __bf16* kh   = qh  + SZ;
    __bf16* vh   = kh  + SZ;
    __bf16* qt   = vh  + SZ;
    __bf16* kt   = qt  + SZ;
    __bf16* vt   = kt  + SZ;
    __bf16* ctxh = vt  + SZ;
    __bf16* ctxt = ctxh + SZ;
    // transposed weights (bf16)
    __bf16* mapT = ctxt + SZ;                       // [512][320]
    __bf16* q1T  = mapT + 512 * 320;                // [512][512] each
    __bf16* k1T  = q1T + 512 * 512;
    __bf16* v1T  = k1T + 512 * 512;
    __bf16* q2T  = v1T + 512 * 512;
    __bf16* k2T  = q2T + 512 * 512;
    __bf16* v2T  = k2T + 512 * 512;
    __bf16* d1T  = v2T + 512 * 512;
    __bf16* d2T  = d1T + 512 * 512;

    compute_ranges<<<dim3(1), dim3(128), 0, stream>>>(batch_head, batch_tail, NTOK, ranges);

    // -- transpose all weights (one dispatch) --
    TransJobs tj;
    tj.src[0] = map_w; tj.dst[0] = mapT; tj.K[0] = 300; tj.ldT[0] = 320;
    const float* wsrc[8] = {q1_w, k1_w, v1_w, q2_w, k2_w, v2_w, d1_w, d2_w};
    __bf16* wdst[8] = {q1T, k1T, v1T, q2T, k2T, v2T, d1T, d2T};
    for (int i = 0; i < 8; ++i) {
        tj.src[i + 1] = wsrc[i]; tj.dst[i + 1] = wdst[i];
        tj.K[i + 1] = 512; tj.ldT[i + 1] = 512;
    }
    transpose_weights<<<dim3(8, 8, 9), dim3(256), 0, stream>>>(tj);

    // -- GEMMs --
    dim3 gblk(256);
    // map: hh = h_head @ map_w + map_b
    gemm3<float, __bf16><<<dim3(8, 64, 1), gblk, 0, stream>>>(
        h_head, h_head, h_head, 300,
        mapT, mapT, mapT, map_b, map_b, map_b,
        hh, hh, hh, 300, 320);
    // qkv head (A = hh bf16)
    gemm3<__bf16, __bf16><<<dim3(8, 64, 3), gblk, 0, stream>>>(
        hh, hh, hh, 512,
        q1T, k1T, v1T, q1_b, k1_b, v1_b,
        qh, kh, vh, 512, 512);
    // qkv tail (A = h_tail fp32)
    gemm3<float, __bf16><<<dim3(8, 64, 3), gblk, 0, stream>>>(
        h_tail, h_tail, h_tail, 512,
        q2T, k2T, v2T, q2_b, k2_b, v2_b,
        qt, kt, vt, 512, 512);

    // -- attention (both sides, one dispatch) --
    attn_mfma<<<dim3(8, 64, 2), dim3(256), 0, stream>>>(
        qh, kt, vh, vt,      // side 0: head queries x tail keys
        qt, kh, vt, vh,      // side 1: tail queries x head keys
        ranges, ctxh, ctxt, NTOK, NTOK);

    // -- output projections (fused, fp32 out) --
    gemm3<__bf16, float><<<dim3(8, 64, 2), gblk, 0, stream>>>(
        ctxh, ctxt, ctxt, 512,
        d1T, d2T, d2T, d1_b, d2_b, d2_b,
        out, out + SZ, out + SZ, 512, 512);
}

// Round 5
// 191.694 us; speedup vs baseline: 3.1695x; 1.0820x over previous
//
#include <hip/hip_runtime.h>
#include <hip/hip_bf16.h>
#include <math.h>

// ---------------------------------------------------------------------------
// CrossModalityMultiHeadAttention  (MI355X / gfx950)
// Round 5:
//   - activations converted to bf16 once (head padded K 300->320)
//   - GEMM upgraded to m97-style: 128x128 tile, BK=32,
//     global_load_lds width-16 staging (no VALU staging, no LDS padding),
//     4 waves 2x2, 16 MFMA : 8 ds_read_b128 per wave per K-step
//   - dispatches: prep(conv+ranges), transpose(9), gemm[map+qkv-tail z=4],
//     gemm[qkv-head z=3], attn(z=2), gemm[out z=2]  == 6 total
// ---------------------------------------------------------------------------

typedef __bf16 bf16x8 __attribute__((ext_vector_type(8)));
typedef float  f32x4  __attribute__((ext_vector_type(4)));

#define HID 512
#define NTOK 4096

#define AS1(p) ((const __attribute__((address_space(1))) void*)(p))
#define AS3(p) ((__attribute__((address_space(3))) void*)(p))

// --------------------------- input prep ------------------------------------
// z=0: h_head [4096][300] fp32 -> hh_bf [4096][320] bf16 (zero pad), plus
//      compute_ranges on block 0.  z=1: h_tail [4096][512] -> ht_bf.
// grid (512, 1, 2): each block converts 8 rows.
__global__ __launch_bounds__(256) void prep_inputs(
    const float* __restrict__ h_head, const float* __restrict__ h_tail,
    const int* __restrict__ bh, const int* __restrict__ bt,
    __bf16* __restrict__ hh_bf, __bf16* __restrict__ ht_bf,
    int* __restrict__ ranges)
{
    const int q = blockIdx.x, z = blockIdx.z, tid = threadIdx.x;

    if (z == 0) {
        if (q == 0 && tid < 128) {
            int b = tid & 63;
            const int* arr = (tid < 64) ? bh : bt;
            int base = (tid < 64) ? 0 : 128;
            int lo = 0, hi = NTOK;
            while (lo < hi) { int mid = (lo + hi) >> 1; if (arr[mid] < b) lo = mid + 1; else hi = mid; }
            int start = lo;
            lo = 0; hi = NTOK;
            while (lo < hi) { int mid = (lo + hi) >> 1; if (arr[mid] <= b) lo = mid + 1; else hi = mid; }
            ranges[base + b] = start;
            ranges[base + 64 + b] = lo;
        }
        // head: 8 rows x 40 chunks (src 300 cols, dst 320)
        for (int idx = tid; idx < 8 * 40; idx += 256) {
            int r   = q * 8 + idx / 40;
            int col = (idx % 40) * 8;
            bf16x8 v;
            if (col + 8 <= 300) {
                float4 f0 = *(const float4*)&h_head[(size_t)r * 300 + col];
                float4 f1 = *(const float4*)&h_head[(size_t)r * 300 + col + 4];
                v[0]=(__bf16)f0.x; v[1]=(__bf16)f0.y; v[2]=(__bf16)f0.z; v[3]=(__bf16)f0.w;
                v[4]=(__bf16)f1.x; v[5]=(__bf16)f1.y; v[6]=(__bf16)f1.z; v[7]=(__bf16)f1.w;
            } else if (col < 300) {  // col == 296: 4 valid + 4 pad
                float4 f0 = *(const float4*)&h_head[(size_t)r * 300 + col];
                v[0]=(__bf16)f0.x; v[1]=(__bf16)f0.y; v[2]=(__bf16)f0.z; v[3]=(__bf16)f0.w;
                v[4]=(__bf16)0.f; v[5]=(__bf16)0.f; v[6]=(__bf16)0.f; v[7]=(__bf16)0.f;
            } else {
                #pragma unroll
                for (int j = 0; j < 8; ++j) v[j] = (__bf16)0.f;
            }
            *(bf16x8*)&hh_bf[(size_t)r * 320 + col] = v;
        }
    } else {
        // tail: 8 rows x 64 chunks
        for (int idx = tid; idx < 8 * 64; idx += 256) {
            int r   = q * 8 + (idx >> 6);
            int col = (idx & 63) * 8;
            float4 f0 = *(const float4*)&h_tail[(size_t)r * 512 + col];
            float4 f1 = *(const float4*)&h_tail[(size_t)r * 512 + col + 4];
            bf16x8 v;
            v[0]=(__bf16)f0.x; v[1]=(__bf16)f0.y; v[2]=(__bf16)f0.z; v[3]=(__bf16)f0.w;
            v[4]=(__bf16)f1.x; v[5]=(__bf16)f1.y; v[6]=(__bf16)f1.z; v[7]=(__bf16)f1.w;
            *(bf16x8*)&ht_bf[(size_t)r * 512 + col] = v;
        }
    }
}

// --------------------------- weight transpose ------------------------------
// W[K][512] fp32 -> WT[512][ldT] bf16 (rows zero-padded K..ldT).
struct TransJobs {
    const float* src[9];
    __bf16*      dst[9];
    int          K[9];
    int          ldT[9];
};

__global__ __launch_bounds__(256) void transpose_weights(TransJobs tj) {
    const int z = blockIdx.z;
    const float* src = tj.src[z];
    __bf16* dst = tj.dst[z];
    const int K = tj.K[z], ldT = tj.ldT[z];
    const int tk = blockIdx.y * 64;
    const int tn = blockIdx.x * 64;
    if (tk >= ldT) return;

    __shared__ __bf16 T[64][72];
    const int tid = threadIdx.x;
    const int r0 = tid >> 4;
    const int c0 = (tid & 15) * 4;
    #pragma unroll
    for (int i = 0; i < 4; ++i) {
        int k = tk + r0 + i * 16;
        float4 v = (k < K) ? *(const float4*)&src[(size_t)k * 512 + tn + c0]
                           : float4{0.f, 0.f, 0.f, 0.f};
        T[r0 + i * 16][c0 + 0] = (__bf16)v.x;
        T[r0 + i * 16][c0 + 1] = (__bf16)v.y;
        T[r0 + i * 16][c0 + 2] = (__bf16)v.z;
        T[r0 + i * 16][c0 + 3] = (__bf16)v.w;
    }
    __syncthreads();

    const int n  = tid >> 2;
    const int kk = (tid & 3) * 16;
    bf16x8 o0, o1;
    #pragma unroll
    for (int j = 0; j < 8; ++j) { o0[j] = T[kk + j][n]; o1[j] = T[kk + 8 + j][n]; }
    __bf16* dp = dst + (size_t)(tn + n) * ldT + tk + kk;
    *(bf16x8*)dp       = o0;
    *(bf16x8*)(dp + 8) = o1;
}

// ------------------------------ GEMM 128x128 -------------------------------
// C[4096,512] = A[4096,Kp] (bf16) @ WT[512,Kp]^T (bf16) + bias; grid.z = job.
// 256 threads = 4 waves (2x2); each wave computes 64x64 via 4x4 16x16 frags.
// Staging: global_load_lds width 16, LDS unpadded [128][32].
struct GemmJobs {
    const __bf16* A[4];
    const __bf16* W[4];
    const float*  bias[4];
    void*         C[4];
    int           Kp[4];
};

template <typename TC>
__global__ __launch_bounds__(256) void gemm128(GemmJobs jobs) {
    __shared__ __align__(16) __bf16 As[128 * 32];
    __shared__ __align__(16) __bf16 Bs[128 * 32];

    const int z = blockIdx.z;
    const __bf16* A    = jobs.A[z];
    const __bf16* W    = jobs.W[z];
    const float*  bias = jobs.bias[z];
    TC*           C    = (TC*)jobs.C[z];
    const int     Kp   = jobs.Kp[z];

    const int tid  = threadIdx.x;
    const int wave = tid >> 6;
    const int lane = tid & 63;
    const int quad = lane >> 4;
    const int l16  = lane & 15;
    const int wy   = wave >> 1;         // 0..1
    const int wx   = wave & 1;          // 0..1
    const int rowBase = blockIdx.y * 128;
    const int colBase = blockIdx.x * 128;

    // staging: chunk c (16 B) -> row c>>2, kchunk c&3. Thread t owns chunks
    // t (rows 0..63) and t+256 (rows 64..127). LDS dest base is wave-uniform.
    const int s_row = tid >> 2;             // 0..63
    const int s_kc  = (tid & 3) * 8;

    f32x4 acc[4][4] = {};

    const __bf16* gA = A + (size_t)(rowBase + s_row) * Kp + s_kc;
    const __bf16* gB = W + (size_t)(colBase + s_row) * Kp + s_kc;
    __bf16* lA0 = &As[wave * 512];
    __bf16* lA1 = &As[2048 + wave * 512];
    __bf16* lB0 = &Bs[wave * 512];
    __bf16* lB1 = &Bs[2048 + wave * 512];

    for (int kt = 0; kt < Kp; kt += 32) {
        __builtin_amdgcn_global_load_lds(AS1(gA + kt),            AS3(lA0), 16, 0, 0);
        __builtin_amdgcn_global_load_lds(AS1(gA + kt + 64 * Kp),  AS3(lA1), 16, 0, 0);
        __builtin_amdgcn_global_load_lds(AS1(gB + kt),            AS3(lB0), 16, 0, 0);
        __builtin_amdgcn_global_load_lds(AS1(gB + kt + 64 * Kp),  AS3(lB1), 16, 0, 0);
        __syncthreads();   // drains vmcnt, LDS tiles ready

        bf16x8 ar[4], br[4];
        #pragma unroll
        for (int i = 0; i < 4; ++i)
            ar[i] = *(const bf16x8*)&As[(wy * 64 + i * 16 + l16) * 32 + quad * 8];
        #pragma unroll
        for (int j = 0; j < 4; ++j)
            br[j] = *(const bf16x8*)&Bs[(wx * 64 + j * 16 + l16) * 32 + quad * 8];
        #pragma unroll
        for (int i = 0; i < 4; ++i)
            #pragma unroll
            for (int j = 0; j < 4; ++j)
                acc[i][j] = __builtin_amdgcn_mfma_f32_16x16x32_bf16(ar[i], br[j], acc[i][j], 0, 0, 0);
        __syncthreads();   // reads done before next stage overwrites
    }

    // epilogue: C/D layout col=l16, row=quad*4+reg
    #pragma unroll
    for (int j = 0; j < 4; ++j) {
        int col = colBase + wx * 64 + j * 16 + l16;
        float bv = bias[col];
        #pragma unroll
        for (int i = 0; i < 4; ++i) {
            #pragma unroll
            for (int r = 0; r < 4; ++r) {
                int row = rowBase + wy * 64 + i * 16 + quad * 4 + r;
                C[(size_t)row * HID + col] = (TC)(acc[i][j][r] + bv);
            }
        }
    }
}

// ------------------------- MFMA flash attention ----------------------------
// grid = (head 8, batch 64, side 2). side 0: head-q x tail-k; side 1: swap.
__global__ __launch_bounds__(256) void attn_mfma(
    const __bf16* __restrict__ Q0, const __bf16* __restrict__ K0,
    const __bf16* __restrict__ Vr0, const __bf16* __restrict__ Vc0,
    const __bf16* __restrict__ Q1, const __bf16* __restrict__ K1,
    const __bf16* __restrict__ Vr1, const __bf16* __restrict__ Vc1,
    const int* __restrict__ ranges,
    __bf16* __restrict__ O0, __bf16* __restrict__ O1,
    int Nq, int Nk)
{
    __shared__ __align__(16) __bf16 Qs[64][72];
    __shared__ __align__(16) __bf16 Ks[64][72];
    __shared__ __align__(16) __bf16 Vt[64][72];   // [dim][key]
    __shared__ __align__(16) __bf16 Ps[64][72];   // [query][key]

    const int z = blockIdx.z;
    const __bf16* Q    = z ? Q1 : Q0;
    const __bf16* Kg   = z ? K1 : K0;
    const __bf16* Vres = z ? Vr1 : Vr0;
    const __bf16* Vctx = z ? Vc1 : Vc0;
    __bf16* Out        = z ? O1 : O0;
    const int* qstart  = z ? ranges + 128 : ranges;
    const int* qend    = z ? ranges + 192 : ranges + 64;
    const int* kstart  = z ? ranges       : ranges + 128;
    const int* kend    = z ? ranges + 64  : ranges + 192;

    const int h = blockIdx.x, b = blockIdx.y;
    const int qs = qstart[b], qe = qend[b];
    const int ts = kstart[b], te = kend[b];
    const int nq = qe - qs, nk = te - ts;
    if (nq <= 0) return;

    const int tid  = threadIdx.x;
    const int wave = tid >> 6;
    const int lane = tid & 63;
    const int quad = lane >> 4;
    const int l16  = lane & 15;
    const int srow = tid >> 2;
    const int scol = (tid & 3) * 16;

    if (nk <= 0) {
        float* meanv = (float*)Qs;
        if (tid < 64) {
            float s = 0.f;
            for (int m = 0; m < Nk; ++m)
                s += (float)Vctx[(size_t)m * HID + h * 64 + tid];
            meanv[tid] = s / (float)Nk;
        }
        __syncthreads();
        int d = tid & 63;
        for (int r = qs + (tid >> 6); r < qe; r += 4) {
            size_t off = (size_t)r * HID + h * 64 + d;
            Out[off] = (__bf16)((float)Vres[off] + meanv[d]);
        }
        return;
    }

    for (int qc = 0; qc < nq; qc += 64) {
        __syncthreads();
        {
            int qg = min(qs + qc + srow, Nq - 1);
            const __bf16* src = Q + (size_t)qg * HID + h * 64 + scol;
            *(bf16x8*)&Qs[srow][scol]     = *(const bf16x8*)src;
            *(bf16x8*)&Qs[srow][scol + 8] = *(const bf16x8*)(src + 8);
        }
        __syncthreads();
        bf16x8 aq0 = *(const bf16x8*)&Qs[wave * 16 + l16][quad * 8];
        bf16x8 aq1 = *(const bf16x8*)&Qs[wave * 16 + l16][32 + quad * 8];

        f32x4 O[4] = {};
        float Mx[4], L[4];
        #pragma unroll
        for (int r = 0; r < 4; ++r) { Mx[r] = -__builtin_inff(); L[r] = 0.f; }

        for (int kc = 0; kc < nk; kc += 64) {
            __syncthreads();
            {
                int kg = min(ts + kc + srow, Nk - 1);
                const __bf16* ksrc = Kg + (size_t)kg * HID + h * 64 + scol;
                *(bf16x8*)&Ks[srow][scol]     = *(const bf16x8*)ksrc;
                *(bf16x8*)&Ks[srow][scol + 8] = *(const bf16x8*)(ksrc + 8);
                const __bf16* vsrc = Vctx + (size_t)kg * HID + h * 64 + scol;
                bf16x8 v0 = *(const bf16x8*)vsrc;
                bf16x8 v1 = *(const bf16x8*)(vsrc + 8);
                #pragma unroll
                for (int j = 0; j < 8; ++j) {
                    Vt[scol + j][srow]     = v0[j];
                    Vt[scol + 8 + j][srow] = v1[j];
                }
            }
            __syncthreads();

            f32x4 S[4] = {};
            #pragma unroll
            for (int c = 0; c < 4; ++c) {
                bf16x8 bk0 = *(const bf16x8*)&Ks[c * 16 + l16][quad * 8];
                bf16x8 bk1 = *(const bf16x8*)&Ks[c * 16 + l16][32 + quad * 8];
                S[c] = __builtin_amdgcn_mfma_f32_16x16x32_bf16(aq0, bk0, S[c], 0, 0, 0);
                S[c] = __builtin_amdgcn_mfma_f32_16x16x32_bf16(aq1, bk1, S[c], 0, 0, 0);
            }

            #pragma unroll
            for (int c = 0; c < 4; ++c) {
                bool valid = (ts + kc + c * 16 + l16) < te;
                #pragma unroll
                for (int r = 0; r < 4; ++r)
                    S[c][r] = valid ? S[c][r] * 0.125f : -__builtin_inff();
            }

            float cm[4], ps[4], alpha[4];
            #pragma unroll
            for (int r = 0; r < 4; ++r) {
                float v = fmaxf(fmaxf(S[0][r], S[1][r]), fmaxf(S[2][r], S[3][r]));
                v = fmaxf(v, __shfl_xor(v, 1, 64));
                v = fmaxf(v, __shfl_xor(v, 2, 64));
                v = fmaxf(v, __shfl_xor(v, 4, 64));
                v = fmaxf(v, __shfl_xor(v, 8, 64));
                cm[r] = v;
            }
            #pragma unroll
            for (int r = 0; r < 4; ++r) {
                float nM = fmaxf(Mx[r], cm[r]);
                alpha[r] = __expf(Mx[r] - nM);
                Mx[r] = nM;
                ps[r] = 0.f;
            }
            #pragma unroll
            for (int c = 0; c < 4; ++c)
                #pragma unroll
                for (int r = 0; r < 4; ++r) {
                    float p = __expf(S[c][r] - Mx[r]);
                    S[c][r] = p;
                    ps[r] += p;
                }
            #pragma unroll
            for (int r = 0; r < 4; ++r) {
                float v = ps[r];
                v += __shfl_xor(v, 1, 64);
                v += __shfl_xor(v, 2, 64);
                v += __shfl_xor(v, 4, 64);
                v += __shfl_xor(v, 8, 64);
                L[r] = L[r] * alpha[r] + v;
            }
            #pragma unroll
            for (int c = 0; c < 4; ++c)
                #pragma unroll
                for (int r = 0; r < 4; ++r)
                    O[c][r] *= alpha[r];

            #pragma unroll
            for (int c = 0; c < 4; ++c)
                #pragma unroll
                for (int r = 0; r < 4; ++r)
                    Ps[wave * 16 + quad * 4 + r][c * 16 + l16] = (__bf16)S[c][r];
            __syncthreads();

            bf16x8 ap0 = *(const bf16x8*)&Ps[wave * 16 + l16][quad * 8];
            bf16x8 ap1 = *(const bf16x8*)&Ps[wave * 16 + l16][32 + quad * 8];
            #pragma unroll
            for (int c = 0; c < 4; ++c) {
                bf16x8 bv0 = *(const bf16x8*)&Vt[c * 16 + l16][quad * 8];
                bf16x8 bv1 = *(const bf16x8*)&Vt[c * 16 + l16][32 + quad * 8];
                O[c] = __builtin_amdgcn_mfma_f32_16x16x32_bf16(ap0, bv0, O[c], 0, 0, 0);
                O[c] = __builtin_amdgcn_mfma_f32_16x16x32_bf16(ap1, bv1, O[c], 0, 0, 0);
            }
        }

        #pragma unroll
        for (int c = 0; c < 4; ++c) {
            int d = h * 64 + c * 16 + l16;
            #pragma unroll
            for (int r = 0; r < 4; ++r) {
                int qrow = qs + qc + wave * 16 + quad * 4 + r;
                if (qrow < qe) {
                    size_t off = (size_t)qrow * HID + d;
                    Out[off] = (__bf16)((float)Vres[off] + O[c][r] / L[r]);
                }
            }
        }
    }
}

// ------------------------------ launcher -----------------------------------
extern "C" void kernel_launch(void* const* d_in, const int* in_sizes, int n_in,
                              void* d_out, int out_size, void* d_ws, size_t ws_size,
                              hipStream_t stream) {
    (void)in_sizes; (void)n_in; (void)out_size; (void)ws_size;

    const float* h_head = (const float*)d_in[0];
    const float* h_tail = (const float*)d_in[1];
    const int* batch_head = (const int*)d_in[2];
    const int* batch_tail = (const int*)d_in[3];
    const float* map_w = (const float*)d_in[4];
    const float* map_b = (const float*)d_in[5];
    const float* q1_w = (const float*)d_in[6];
    const float* q1_b = (const float*)d_in[7];
    const float* k1_w = (const float*)d_in[8];
    const float* k1_b = (const float*)d_in[9];
    const float* v1_w = (const float*)d_in[10];
    const float* v1_b = (const float*)d_in[11];
    const float* q2_w = (const float*)d_in[12];
    const float* q2_b = (const float*)d_in[13];
    const float* k2_w = (const float*)d_in[14];
    const float* k2_b = (const float*)d_in[15];
    const float* v2_w = (const float*)d_in[16];
    const float* v2_b = (const float*)d_in[17];
    const float* d1_w = (const float*)d_in[18];
    const float* d1_b = (const float*)d_in[19];
    const float* d2_w = (const float*)d_in[20];
    const float* d2_b = (const float*)d_in[21];

    float* out = (float*)d_out;

    const size_t SZ = (size_t)NTOK * HID;
    char* ws = (char*)d_ws;
    int* ranges = (int*)ws;                         // 256 ints
    __bf16* hh   = (__bf16*)(ws + 1024);
    __bf16* qh   = hh  + SZ;
    __bf16* kh   = qh  + SZ;
    __bf16* vh   = kh  + SZ;
    __bf16* qt   = vh  + SZ;
    __bf16* kt   = qt  + SZ;
    __bf16* vt   = kt  + SZ;
    __bf16* ctxh = vt  + SZ;
    __bf16* ctxt = ctxh + SZ;
    __bf16* mapT = ctxt + SZ;                       // [512][320]
    __bf16* q1T  = mapT + 512 * 320;                // [512][512] each
    __bf16* k1T  = q1T + 512 * 512;
    __bf16* v1T  = k1T + 512 * 512;
    __bf16* q2T  = v1T + 512 * 512;
    __bf16* k2T  = q2T + 512 * 512;
    __bf16* v2T  = k2T + 512 * 512;
    __bf16* d1T  = v2T + 512 * 512;
    __bf16* d2T  = d1T + 512 * 512;
    __bf16* hh_bf = d2T + 512 * 512;                // [4096][320]
    __bf16* ht_bf = hh_bf + (size_t)NTOK * 320;     // [4096][512]

    // prep: convert activations + ranges
    prep_inputs<<<dim3(512, 1, 2), dim3(256), 0, stream>>>(
        h_head, h_tail, batch_head, batch_tail, hh_bf, ht_bf, ranges);

    // transpose all weights
    TransJobs tj;
    tj.src[0] = map_w; tj.dst[0] = mapT; tj.K[0] = 300; tj.ldT[0] = 320;
    const float* wsrc[8] = {q1_w, k1_w, v1_w, q2_w, k2_w, v2_w, d1_w, d2_w};
    __bf16* wdst[8] = {q1T, k1T, v1T, q2T, k2T, v2T, d1T, d2T};
    for (int i = 0; i < 8; ++i) {
        tj.src[i + 1] = wsrc[i]; tj.dst[i + 1] = wdst[i];
        tj.K[i + 1] = 512; tj.ldT[i + 1] = 512;
    }
    transpose_weights<<<dim3(8, 8, 9), dim3(256), 0, stream>>>(tj);

    // GEMM group 1: map + qkv-tail (inputs only)
    {
        GemmJobs j;
        j.A[0] = hh_bf; j.W[0] = mapT; j.bias[0] = map_b; j.C[0] = hh; j.Kp[0] = 320;
        j.A[1] = ht_bf; j.W[1] = q2T; j.bias[1] = q2_b; j.C[1] = qt; j.Kp[1] = 512;
        j.A[2] = ht_bf; j.W[2] = k2T; j.bias[2] = k2_b; j.C[2] = kt; j.Kp[2] = 512;
        j.A[3] = ht_bf; j.W[3] = v2T; j.bias[3] = v2_b; j.C[3] = vt; j.Kp[3] = 512;
        gemm128<__bf16><<<dim3(4, 32, 4), dim3(256), 0, stream>>>(j);
    }
    // GEMM group 2: qkv-head (depends on hh)
    {
        GemmJobs j;
        j.A[0] = hh; j.W[0] = q1T; j.bias[0] = q1_b; j.C[0] = qh; j.Kp[0] = 512;
        j.A[1] = hh; j.W[1] = k1T; j.bias[1] = k1_b; j.C[1] = kh; j.Kp[1] = 512;
        j.A[2] = hh; j.W[2] = v1T; j.bias[2] = v1_b; j.C[2] = vh; j.Kp[2] = 512;
        j.A[3] = hh; j.W[3] = v1T; j.bias[3] = v1_b; j.C[3] = vh; j.Kp[3] = 512;
        gemm128<__bf16><<<dim3(4, 32, 3), dim3(256), 0, stream>>>(j);
    }

    // attention (both sides, one dispatch)
    attn_mfma<<<dim3(8, 64, 2), dim3(256), 0, stream>>>(
        qh, kt, vh, vt,
        qt, kh, vt, vh,
        ranges, ctxh, ctxt, NTOK, NTOK);

    // GEMM group 3: output projections (fp32 out into d_out)
    {
        GemmJobs j;
        j.A[0] = ctxh; j.W[0] = d1T; j.bias[0] = d1_b; j.C[0] = out;      j.Kp[0] = 512;
        j.A[1] = ctxt; j.W[1] = d2T; j.bias[1] = d2_b; j.C[1] = out + SZ; j.Kp[1] = 512;
        j.A[2] = ctxt; j.W[2] = d2T; j.bias[2] = d2_b; j.C[2] = out + SZ; j.Kp[2] = 512;
        j.A[3] = ctxt; j.W[3] = d2T; j.bias[3] = d2_b; j.C[3] = out + SZ; j.Kp[3] = 512;
        gemm128<float><<<dim3(4, 32, 2), dim3(256), 0, stream>>>(j);
    }
}